// Round 6
// baseline (198.257 us; speedup 1.0000x reference)
//
#include <hip/hip_runtime.h>
#include <math.h>

#define DF 8192
#define NT 512

// XOR swizzle on float2 slot index: bank bits 1-4 ^= slot bits 6-9.
// Preserves bit 0 (b128 pairs stay adjacent, ordered, 16B-aligned).
// Every sweep pattern in this kernel lands at <=2-way bank aliasing (free).
#define SW(i) ((i) ^ (((i) >> 5) & 30))

// wave-private sync: all my LDS writes complete; compiler may not reorder LDS ops across
#define WAVE_SYNC asm volatile("s_waitcnt lgkmcnt(0)" ::: "memory")

__device__ __forceinline__ float2 cmul(float2 a, float2 b) {
    return make_float2(a.x * b.x - a.y * b.y, a.x * b.y + a.y * b.x);
}
__device__ __forceinline__ float2 cadd(float2 a, float2 b) { return make_float2(a.x + b.x, a.y + b.y); }
__device__ __forceinline__ float2 csub(float2 a, float2 b) { return make_float2(a.x - b.x, a.y - b.y); }
__device__ __forceinline__ float2 cmuli(float2 a)  { return make_float2(-a.y, a.x); }   // * +i
__device__ __forceinline__ float2 cmulmi(float2 a) { return make_float2(a.y, -a.x); }   // * -i

#define RT_C 0.92387953251128674f
#define RT_S 0.38268343236508977f
#define RT_H 0.70710678118654752f

__device__ __forceinline__ float2 rootF(int j) {   // exp(-i*pi*j/8)
    switch (j & 7) {
        case 0:  return make_float2( 1.f,   0.f  );
        case 1:  return make_float2( RT_C, -RT_S );
        case 2:  return make_float2( RT_H, -RT_H );
        case 3:  return make_float2( RT_S, -RT_C );
        case 4:  return make_float2( 0.f,  -1.f  );
        case 5:  return make_float2(-RT_S, -RT_C );
        case 6:  return make_float2(-RT_H, -RT_H );
        default: return make_float2(-RT_C, -RT_S );
    }
}
__device__ __forceinline__ float2 rootI(int j) {   // exp(+i*pi*j/8)
    float2 r = rootF(j);
    return make_float2(r.x, -r.y);
}

__device__ __forceinline__ int brev9(int x) { return (int)(__brev((unsigned)x) >> 23); }

// ---- DIF butterflies ----
__device__ __forceinline__ void bf_dif(float2& a, float2& b, float2 W) {
    float2 d = csub(a, b);
    a = cadd(a, b);
    b = cmul(d, W);
}
__device__ __forceinline__ void bf_dif1(float2& a, float2& b) {      // W = 1
    float2 d = csub(a, b);
    a = cadd(a, b);
    b = d;
}
__device__ __forceinline__ void bf_difmi(float2& a, float2& b) {     // W = -i
    float2 d = csub(a, b);
    a = cadd(a, b);
    b = cmulmi(d);
}
// ---- DIT butterflies ----
__device__ __forceinline__ void bf_dit(float2& a, float2& b, float2 W) {
    float2 bw = cmul(b, W);
    float2 ta = a;
    a = cadd(ta, bw);
    b = csub(ta, bw);
}
__device__ __forceinline__ void bf_dit1(float2& a, float2& b) {
    float2 tb = b, ta = a;
    a = cadd(ta, tb);
    b = csub(ta, tb);
}
__device__ __forceinline__ void bf_diti(float2& a, float2& b) {
    float2 bw = cmuli(b);
    float2 ta = a;
    a = cadd(ta, bw);
    b = csub(ta, bw);
}

// 4 radix-2 DIF stages on 16 register elements, base twiddle wb (verified R3).
__device__ __forceinline__ void fft16_dif(float2 v[16], float2 wb) {
    const float2 wb2 = cmul(wb, wb);
    const float2 wb4 = cmul(wb2, wb2);
    const float2 wb8 = cmul(wb4, wb4);
    #pragma unroll
    for (int m = 0; m < 8; ++m) bf_dif(v[m], v[m + 8], cmul(wb, rootF(m)));
    #pragma unroll
    for (int m = 0; m < 4; ++m) {
        float2 W = cmul(wb2, rootF(2 * m));
        bf_dif(v[m],     v[m + 4],  W);
        bf_dif(v[8 + m], v[12 + m], W);
    }
    #pragma unroll
    for (int g = 0; g < 4; ++g)
        #pragma unroll
        for (int m = 0; m < 2; ++m)
            bf_dif(v[4 * g + m], v[4 * g + m + 2], cmul(wb4, rootF(4 * m)));
    #pragma unroll
    for (int g = 0; g < 8; ++g) bf_dif(v[2 * g], v[2 * g + 1], wb8);
}

// 3 radix-2 DIF stages (dm=4,2,1) for sub-A: h=256,128,64; wA = exp(-i*pi*l/256).
__device__ __forceinline__ void fft16_dif3(float2 v[16], float2 wA) {
    const float2 wA2 = cmul(wA, wA);
    const float2 wA4 = cmul(wA2, wA2);
    #pragma unroll
    for (int m = 0; m < 4; ++m) {              // h=256: W = wA*rootF(2m)
        float2 W = cmul(wA, rootF(2 * m));
        bf_dif(v[m],     v[m + 4],  W);
        bf_dif(v[8 + m], v[12 + m], W);
    }
    #pragma unroll
    for (int a = 0; a < 4; ++a)                // h=128: W = wA^2*rootF(4q)
        #pragma unroll
        for (int q = 0; q < 2; ++q)
            bf_dif(v[4 * a + q], v[4 * a + q + 2], cmul(wA2, rootF(4 * q)));
    #pragma unroll
    for (int c = 0; c < 8; ++c)                // h=64: W = wA^4
        bf_dif(v[2 * c], v[2 * c + 1], wA4);
}

// 3 radix-2 DIT stages on 8 elements; wq = exp(+i*pi*k/(4*h_first)) (verified R3/R5).
__device__ __forceinline__ void fft8_dit(float2 v[8], float2 wq) {
    const float2 wq2 = cmul(wq, wq);
    const float2 wq4 = cmul(wq2, wq2);
    #pragma unroll
    for (int g = 0; g < 4; ++g) bf_dit(v[2 * g], v[2 * g + 1], wq4);
    const float2 iwq2 = cmuli(wq2);
    #pragma unroll
    for (int g = 0; g < 2; ++g) {
        bf_dit(v[4 * g],     v[4 * g + 2], wq2);
        bf_dit(v[4 * g + 1], v[4 * g + 3], iwq2);
    }
    bf_dit(v[0], v[4], wq);
    bf_dit(v[1], v[5], cmul(wq, make_float2(RT_H, RT_H)));
    bf_dit(v[2], v[6], cmuli(wq));
    bf_dit(v[3], v[7], cmul(wq, make_float2(-RT_H, RT_H)));
}
// same with wq = 1 (h=1,2,4; all-constant twiddles)
__device__ __forceinline__ void fft8_dit1(float2 v[8]) {
    #pragma unroll
    for (int g = 0; g < 4; ++g) bf_dit1(v[2 * g], v[2 * g + 1]);
    #pragma unroll
    for (int g = 0; g < 2; ++g) {
        bf_dit1(v[4 * g],     v[4 * g + 2]);
        bf_diti(v[4 * g + 1], v[4 * g + 3]);
    }
    bf_dit1(v[0], v[4]);
    bf_dit (v[1], v[5], make_float2(RT_H, RT_H));
    bf_diti(v[2], v[6]);
    bf_dit (v[3], v[7], make_float2(-RT_H, RT_H));
}

// Hermitian product + half-size-IFFT input prep (verified R3/R5).
__device__ __forceinline__ float2 mega_combine(float2 A, float2 B, float2 PA, float2 PB,
                                               float2 W, float invN) {
    float X1r = 0.5f * (A.x + PB.x), X1i = 0.5f * (A.y - PB.y);
    float Y1r = 0.5f * (A.y + PB.y), Y1i = 0.5f * (PB.x - A.x);
    float2 P1 = make_float2((X1r * Y1r - X1i * Y1i) * invN, (X1r * Y1i + X1i * Y1r) * invN);
    float X2r = 0.5f * (B.x + PA.x), X2i = 0.5f * (B.y - PA.y);
    float Y2r = 0.5f * (B.y + PA.y), Y2i = 0.5f * (PA.x - B.x);
    float2 P2 = make_float2((X2r * Y2r - X2i * Y2i) * invN, (X2r * Y2i + X2i * Y2r) * invN);
    float2 S = cadd(P1, P2);
    float2 D = csub(P1, P2);
    float2 Dw = cmul(D, W);
    return make_float2(S.x - Dw.y, S.y + Dw.x);
}

// Structure: F1 (cross-chunk, h=4096..512) | wave-private chunk: sub-A (256,128,64),
// sub-B (32,16,8,4), sub-C (2,1) | MEGA (Hermitian product + inv h=1,2,4) |
// wave-private inv chunk: sub-a (8,16,32), sub-b (64,128,256) | final (512,1024,2048) | LN+L2.
__global__ __launch_bounds__(NT, 4)
void mcb6(const float* __restrict__ x, const float* __restrict__ y,
          const float* __restrict__ s1, const float* __restrict__ s2,
          const float* __restrict__ gamma, const float* __restrict__ beta,
          const int* __restrict__ h1, const int* __restrict__ h2,
          float* __restrict__ out)
{
    __shared__ float2 z[DF];   // 64 KB
    const int t  = threadIdx.x;
    const int l  = t & 63;
    const int wv = t >> 6;
    const int row = blockIdx.x;

    // ---- zero ----
    {
        float4* z4 = (float4*)z;
        #pragma unroll
        for (int m = 0; m < 8; ++m) z4[t + NT * m] = make_float4(0.f, 0.f, 0.f, 0.f);
    }
    __syncthreads();

    // ---- count sketches: x*s1 -> .x, y*s2 -> .y ----
    {
        float4 xv = ((const float4*)(x + (size_t)row * 2048))[t];
        float4 sv = ((const float4*)s1)[t];
        int4   hv = ((const int4*)h1)[t];
        atomicAdd(&z[SW(hv.x)].x, xv.x * sv.x);
        atomicAdd(&z[SW(hv.y)].x, xv.y * sv.y);
        atomicAdd(&z[SW(hv.z)].x, xv.z * sv.z);
        atomicAdd(&z[SW(hv.w)].x, xv.w * sv.w);
        float2 yv = ((const float2*)(y + (size_t)row * 1024))[t];
        float2 tv = ((const float2*)s2)[t];
        int2   hw = ((const int2*)h2)[t];
        atomicAdd(&z[SW(hw.x)].y, yv.x * tv.x);
        atomicAdd(&z[SW(hw.y)].y, yv.y * tv.y);
    }
    __syncthreads();

    float sn, cs;
    float2 v[16];

    // ---------- F1: h=4096,2048,1024,512 ; slot = t + 512m (cross-chunk) ----------
    #pragma unroll
    for (int m = 0; m < 16; ++m) v[m] = z[SW(t + 512 * m)];
    __sincosf(-(float)M_PI / 4096.f * (float)t, &sn, &cs);
    fft16_dif(v, make_float2(cs, sn));
    #pragma unroll
    for (int m = 0; m < 16; ++m) z[SW(t + 512 * m)] = v[m];
    __syncthreads();

    const int cb = wv << 10;   // wave-private 1024-element chunk base

    // ---------- sub-A: slot = cb + l + 64m ; h=256,128,64 ----------
    #pragma unroll
    for (int m = 0; m < 16; ++m) v[m] = z[SW(cb + l + 64 * m)];
    __sincosf(-(float)M_PI / 256.f * (float)l, &sn, &cs);
    fft16_dif3(v, make_float2(cs, sn));
    #pragma unroll
    for (int m = 0; m < 16; ++m) z[SW(cb + l + 64 * m)] = v[m];
    WAVE_SYNC;

    // ---------- sub-B: slot = cb + (l&3) + 4m + 64*(l>>2) ; h=32,16,8,4 ----------
    {
        const int b = cb + (l & 3) + ((l >> 2) << 6);
        #pragma unroll
        for (int m = 0; m < 16; ++m) v[m] = z[SW(b + 4 * m)];
        __sincosf(-(float)M_PI / 32.f * (float)(l & 3), &sn, &cs);
        fft16_dif(v, make_float2(cs, sn));
        #pragma unroll
        for (int m = 0; m < 16; ++m) z[SW(b + 4 * m)] = v[m];
    }
    WAVE_SYNC;

    // ---------- sub-C: slot = cb + 16l + m ; h=2,1 ; results stay in regs ----------
    {
        const int b = cb + 16 * l;
        #pragma unroll
        for (int c = 0; c < 8; ++c) {
            float4 q = *(const float4*)&z[SW(b + 2 * c)];
            v[2 * c]     = make_float2(q.x, q.y);
            v[2 * c + 1] = make_float2(q.z, q.w);
        }
        #pragma unroll
        for (int a = 0; a < 4; ++a) {            // h=2: W = {1, -i}
            bf_dif1 (v[4 * a],     v[4 * a + 2]);
            bf_difmi(v[4 * a + 1], v[4 * a + 3]);
        }
        #pragma unroll
        for (int c = 0; c < 8; ++c) bf_dif1(v[2 * c], v[2 * c + 1]);   // h=1
        #pragma unroll
        for (int c = 0; c < 8; ++c)
            *(float4*)&z[SW(b + 2 * c)] =
                make_float4(v[2 * c].x, v[2 * c].y, v[2 * c + 1].x, v[2 * c + 1].y);
    }
    __syncthreads();

    // ---------- MEGA: pair j=8t+g holds (Z[kappa], Z[kappa+4096]), kappa=512*brev3(g)+brev9(t).
    // Partner pair at thread tp=brev9(512-R), pair 7-g; t==0: own pairs TBL (swap at g==0).
    float2 u[8];
    {
        const int R  = brev9(t);
        const int tp = (R == 0) ? 0 : brev9(512 - R);
        __sincosf((float)M_PI / 4096.f * (float)R, &sn, &cs);
        const float2 wR = make_float2(cs, sn);      // exp(+i*pi*R/4096)
        const float invN = 1.f / 8192.f;
        const int MB[8]  = {0, 4, 2, 6, 1, 5, 3, 7};   // brev3(g)
        const int TBL[8] = {0, 1, 3, 2, 7, 6, 5, 4};
        #pragma unroll
        for (int g = 0; g < 8; ++g) {
            int ps = (t == 0) ? (2 * TBL[g]) : (16 * tp + 2 * (7 - g));
            float4 r = *(const float4*)&z[SW(ps)];
            float2 PA = make_float2(r.x, r.y);
            float2 PB = make_float2(r.z, r.w);
            if (t == 0 && g == 0) { float2 s0 = PA; PA = PB; PB = s0; }   // kappa=0 self-pair
            u[g] = mega_combine(v[2 * g], v[2 * g + 1], PA, PB,
                                cmul(wR, rootI(MB[g])), invN);
        }
        fft8_dit1(u);   // inverse h=1,2,4
    }
    __syncthreads();    // all partner reads complete before overwriting with u
    #pragma unroll
    for (int c = 0; c < 4; ++c)
        *(float4*)&z[SW(8 * t + 2 * c)] =
            make_float4(u[2 * c].x, u[2 * c].y, u[2 * c + 1].x, u[2 * c + 1].y);
    WAVE_SYNC;          // sub-a reads only this wave's own u-writes

    const int b2 = wv << 9;   // wave-private 512-element inverse chunk base

    // ---------- inv sub-a: slot = b2 + (l&7) + 8m + 64*(l>>3) ; h=8,16,32 ----------
    {
        const int b = b2 + (l & 7) + ((l >> 3) << 6);
        #pragma unroll
        for (int m = 0; m < 8; ++m) u[m] = z[SW(b + 8 * m)];
        __sincosf((float)M_PI / 32.f * (float)(l & 7), &sn, &cs);
        fft8_dit(u, make_float2(cs, sn));
        #pragma unroll
        for (int m = 0; m < 8; ++m) z[SW(b + 8 * m)] = u[m];
    }
    WAVE_SYNC;

    // ---------- inv sub-b: slot = b2 + l + 64m ; h=64,128,256 ----------
    {
        const int b = b2 + l;
        #pragma unroll
        for (int m = 0; m < 8; ++m) u[m] = z[SW(b + 64 * m)];
        __sincosf((float)M_PI / 256.f * (float)l, &sn, &cs);
        fft8_dit(u, make_float2(cs, sn));
        #pragma unroll
        for (int m = 0; m < 8; ++m) z[SW(b + 64 * m)] = u[m];
    }
    __syncthreads();

    // ---------- final: slot = t + 512m ; h=512,1024,2048 ; LN + L2 from regs ----------
    #pragma unroll
    for (int m = 0; m < 8; ++m) u[m] = z[SW(t + 512 * m)];
    __sincosf((float)M_PI / 2048.f * (float)t, &sn, &cs);
    fft8_dit(u, make_float2(cs, sn));
    // u[m] = complex at n = t+512m: fused[2n] = .x, fused[2n+1] = .y

    float lsum = 0.f, lsq = 0.f;
    #pragma unroll
    for (int m = 0; m < 8; ++m) {
        lsum += u[m].x + u[m].y;
        lsq  += u[m].x * u[m].x + u[m].y * u[m].y;
    }
    #pragma unroll
    for (int k = 32; k >= 1; k >>= 1) { lsum += __shfl_xor(lsum, k); lsq += __shfl_xor(lsq, k); }
    __syncthreads();                 // all final-sweep reads complete before stash
    if (l == 0) z[wv] = make_float2(lsum, lsq);
    __syncthreads();
    float tsum = 0.f, tsq = 0.f;
    #pragma unroll
    for (int w2 = 0; w2 < 8; ++w2) { tsum += z[w2].x; tsq += z[w2].y; }
    const float mu   = tsum * (1.f / (float)DF);
    const float var  = tsq * (1.f / (float)DF) - mu * mu;
    const float rstd = rsqrtf(var + 1e-5f);

    const float2* g2  = (const float2*)gamma;
    const float2* bt2 = (const float2*)beta;
    float lsq2 = 0.f;
    #pragma unroll
    for (int m = 0; m < 8; ++m) {
        int i = t + 512 * m;
        float2 g = g2[i], bb = bt2[i];
        float ne = (u[m].x - mu) * rstd * g.x + bb.x;
        float no = (u[m].y - mu) * rstd * g.y + bb.y;
        u[m] = make_float2(ne, no);
        lsq2 += ne * ne + no * no;
    }
    #pragma unroll
    for (int k = 32; k >= 1; k >>= 1) lsq2 += __shfl_xor(lsq2, k);
    if (l == 0) z[8 + wv].x = lsq2;
    __syncthreads();
    float t2 = 0.f;
    #pragma unroll
    for (int w2 = 0; w2 < 8; ++w2) t2 += z[8 + w2].x;
    const float inv = 1.f / fmaxf(sqrtf(t2), 1e-12f);

    float2* o2 = (float2*)(out + (size_t)row * DF);
    #pragma unroll
    for (int m = 0; m < 8; ++m)
        o2[t + 512 * m] = make_float2(u[m].x * inv, u[m].y * inv);
}

extern "C" void kernel_launch(void* const* d_in, const int* in_sizes, int n_in,
                              void* d_out, int out_size, void* d_ws, size_t ws_size,
                              hipStream_t stream) {
    const float* x     = (const float*)d_in[0];
    const float* y     = (const float*)d_in[1];
    const float* s1    = (const float*)d_in[2];
    const float* s2    = (const float*)d_in[3];
    const float* gamma = (const float*)d_in[4];
    const float* beta  = (const float*)d_in[5];
    const int*   h1    = (const int*)d_in[6];
    const int*   h2    = (const int*)d_in[7];
    float* out = (float*)d_out;

    hipLaunchKernelGGL(mcb6, dim3(4096), dim3(NT), 0, stream,
                       x, y, s1, s2, gamma, beta, h1, h2, out);
}

// Round 7
// 185.146 us; speedup vs baseline: 1.0708x; 1.0708x over previous
//
#include <hip/hip_runtime.h>
#include <math.h>

#define DF 8192
#define NT 512

// XOR swizzle on float2 slot index: slot bits 1-4 ^= slot bits 4-8 (shifted).
// Preserves bit 0 (b128 pairs stay adjacent, ordered, 16B-aligned).
// Verified per-pattern: every structured sweep in this kernel is <=2-way per
// half-wave (free); b128 pair-patterns spread base-banks 4 lanes/quad.
#define SW(i) ((i) ^ (((i) >> 4) & 30))

// wave-private sync: all my LDS writes complete; compiler may not reorder LDS ops across
#define WAVE_SYNC asm volatile("s_waitcnt lgkmcnt(0)" ::: "memory")

__device__ __forceinline__ float2 cmul(float2 a, float2 b) {
    return make_float2(a.x * b.x - a.y * b.y, a.x * b.y + a.y * b.x);
}
__device__ __forceinline__ float2 cadd(float2 a, float2 b) { return make_float2(a.x + b.x, a.y + b.y); }
__device__ __forceinline__ float2 csub(float2 a, float2 b) { return make_float2(a.x - b.x, a.y - b.y); }
__device__ __forceinline__ float2 cmuli(float2 a)  { return make_float2(-a.y, a.x); }   // * +i
__device__ __forceinline__ float2 cmulmi(float2 a) { return make_float2(a.y, -a.x); }   // * -i

#define RT_C 0.92387953251128674f
#define RT_S 0.38268343236508977f
#define RT_H 0.70710678118654752f

__device__ __forceinline__ float2 rootF(int j) {   // exp(-i*pi*j/8)
    switch (j & 7) {
        case 0:  return make_float2( 1.f,   0.f  );
        case 1:  return make_float2( RT_C, -RT_S );
        case 2:  return make_float2( RT_H, -RT_H );
        case 3:  return make_float2( RT_S, -RT_C );
        case 4:  return make_float2( 0.f,  -1.f  );
        case 5:  return make_float2(-RT_S, -RT_C );
        case 6:  return make_float2(-RT_H, -RT_H );
        default: return make_float2(-RT_C, -RT_S );
    }
}
__device__ __forceinline__ float2 rootI(int j) {   // exp(+i*pi*j/8)
    float2 r = rootF(j);
    return make_float2(r.x, -r.y);
}

__device__ __forceinline__ int brev9(int x) { return (int)(__brev((unsigned)x) >> 23); }

// ---- DIF butterflies ----
__device__ __forceinline__ void bf_dif(float2& a, float2& b, float2 W) {
    float2 d = csub(a, b);
    a = cadd(a, b);
    b = cmul(d, W);
}
__device__ __forceinline__ void bf_dif1(float2& a, float2& b) {      // W = 1
    float2 d = csub(a, b);
    a = cadd(a, b);
    b = d;
}
__device__ __forceinline__ void bf_difmi(float2& a, float2& b) {     // W = -i
    float2 d = csub(a, b);
    a = cadd(a, b);
    b = cmulmi(d);
}
// ---- DIT butterflies ----
__device__ __forceinline__ void bf_dit(float2& a, float2& b, float2 W) {
    float2 bw = cmul(b, W);
    float2 ta = a;
    a = cadd(ta, bw);
    b = csub(ta, bw);
}
__device__ __forceinline__ void bf_dit1(float2& a, float2& b) {
    float2 tb = b, ta = a;
    a = cadd(ta, tb);
    b = csub(ta, tb);
}
__device__ __forceinline__ void bf_diti(float2& a, float2& b) {
    float2 bw = cmuli(b);
    float2 ta = a;
    a = cadd(ta, bw);
    b = csub(ta, bw);
}

// 4 radix-2 DIF stages on 16 register elements, base twiddle wb (verified R3).
__device__ __forceinline__ void fft16_dif(float2 v[16], float2 wb) {
    const float2 wb2 = cmul(wb, wb);
    const float2 wb4 = cmul(wb2, wb2);
    const float2 wb8 = cmul(wb4, wb4);
    #pragma unroll
    for (int m = 0; m < 8; ++m) bf_dif(v[m], v[m + 8], cmul(wb, rootF(m)));
    #pragma unroll
    for (int m = 0; m < 4; ++m) {
        float2 W = cmul(wb2, rootF(2 * m));
        bf_dif(v[m],     v[m + 4],  W);
        bf_dif(v[8 + m], v[12 + m], W);
    }
    #pragma unroll
    for (int g = 0; g < 4; ++g)
        #pragma unroll
        for (int m = 0; m < 2; ++m)
            bf_dif(v[4 * g + m], v[4 * g + m + 2], cmul(wb4, rootF(4 * m)));
    #pragma unroll
    for (int g = 0; g < 8; ++g) bf_dif(v[2 * g], v[2 * g + 1], wb8);
}

// 3 radix-2 DIF stages (dm=4,2,1) for sub-A: h=256,128,64; wA = exp(-i*pi*l/256).
__device__ __forceinline__ void fft16_dif3(float2 v[16], float2 wA) {
    const float2 wA2 = cmul(wA, wA);
    const float2 wA4 = cmul(wA2, wA2);
    #pragma unroll
    for (int m = 0; m < 4; ++m) {              // h=256: W = wA*rootF(2m)
        float2 W = cmul(wA, rootF(2 * m));
        bf_dif(v[m],     v[m + 4],  W);
        bf_dif(v[8 + m], v[12 + m], W);
    }
    #pragma unroll
    for (int a = 0; a < 4; ++a)                // h=128: W = wA^2*rootF(4q)
        #pragma unroll
        for (int q = 0; q < 2; ++q)
            bf_dif(v[4 * a + q], v[4 * a + q + 2], cmul(wA2, rootF(4 * q)));
    #pragma unroll
    for (int c = 0; c < 8; ++c)                // h=64: W = wA^4
        bf_dif(v[2 * c], v[2 * c + 1], wA4);
}

// 3 radix-2 DIT stages on 8 elements; wq = exp(+i*pi*k/(4*h_first)) (verified R3/R5).
__device__ __forceinline__ void fft8_dit(float2 v[8], float2 wq) {
    const float2 wq2 = cmul(wq, wq);
    const float2 wq4 = cmul(wq2, wq2);
    #pragma unroll
    for (int g = 0; g < 4; ++g) bf_dit(v[2 * g], v[2 * g + 1], wq4);
    const float2 iwq2 = cmuli(wq2);
    #pragma unroll
    for (int g = 0; g < 2; ++g) {
        bf_dit(v[4 * g],     v[4 * g + 2], wq2);
        bf_dit(v[4 * g + 1], v[4 * g + 3], iwq2);
    }
    bf_dit(v[0], v[4], wq);
    bf_dit(v[1], v[5], cmul(wq, make_float2(RT_H, RT_H)));
    bf_dit(v[2], v[6], cmuli(wq));
    bf_dit(v[3], v[7], cmul(wq, make_float2(-RT_H, RT_H)));
}
// same with wq = 1 (h=1,2,4; all-constant twiddles)
__device__ __forceinline__ void fft8_dit1(float2 v[8]) {
    #pragma unroll
    for (int g = 0; g < 4; ++g) bf_dit1(v[2 * g], v[2 * g + 1]);
    #pragma unroll
    for (int g = 0; g < 2; ++g) {
        bf_dit1(v[4 * g],     v[4 * g + 2]);
        bf_diti(v[4 * g + 1], v[4 * g + 3]);
    }
    bf_dit1(v[0], v[4]);
    bf_dit (v[1], v[5], make_float2(RT_H, RT_H));
    bf_diti(v[2], v[6]);
    bf_dit (v[3], v[7], make_float2(-RT_H, RT_H));
}

// Hermitian product + half-size-IFFT input prep (verified R3/R5).
__device__ __forceinline__ float2 mega_combine(float2 A, float2 B, float2 PA, float2 PB,
                                               float2 W, float invN) {
    float X1r = 0.5f * (A.x + PB.x), X1i = 0.5f * (A.y - PB.y);
    float Y1r = 0.5f * (A.y + PB.y), Y1i = 0.5f * (PB.x - A.x);
    float2 P1 = make_float2((X1r * Y1r - X1i * Y1i) * invN, (X1r * Y1i + X1i * Y1r) * invN);
    float X2r = 0.5f * (B.x + PA.x), X2i = 0.5f * (B.y - PA.y);
    float Y2r = 0.5f * (B.y + PA.y), Y2i = 0.5f * (PA.x - B.x);
    float2 P2 = make_float2((X2r * Y2r - X2i * Y2i) * invN, (X2r * Y2i + X2i * Y2r) * invN);
    float2 S = cadd(P1, P2);
    float2 D = csub(P1, P2);
    float2 Dw = cmul(D, W);
    return make_float2(S.x - Dw.y, S.y + Dw.x);
}

// Structure: F1 (cross-chunk, h=4096..512) | wave-private chunk: sub-A (256,128,64),
// sub-B (32,16,8,4), sub-C (2,1) | MEGA (Hermitian product + inv h=1,2,4) |
// wave-private inv chunk: sub-a (8,16,32), sub-b (64,128,256) | final (512,1024,2048) | LN+L2.
__global__ __launch_bounds__(NT, 4)
void mcb7(const float* __restrict__ x, const float* __restrict__ y,
          const float* __restrict__ s1, const float* __restrict__ s2,
          const float* __restrict__ gamma, const float* __restrict__ beta,
          const int* __restrict__ h1, const int* __restrict__ h2,
          float* __restrict__ out)
{
    __shared__ float2 z[DF];   // 64 KB
    const int t  = threadIdx.x;
    const int l  = t & 63;
    const int wv = t >> 6;
    const int row = blockIdx.x;

    // ---- zero ----
    {
        float4* z4 = (float4*)z;
        #pragma unroll
        for (int m = 0; m < 8; ++m) z4[t + NT * m] = make_float4(0.f, 0.f, 0.f, 0.f);
    }
    __syncthreads();

    // ---- count sketches: x*s1 -> .x, y*s2 -> .y ----
    {
        float4 xv = ((const float4*)(x + (size_t)row * 2048))[t];
        float4 sv = ((const float4*)s1)[t];
        int4   hv = ((const int4*)h1)[t];
        atomicAdd(&z[SW(hv.x)].x, xv.x * sv.x);
        atomicAdd(&z[SW(hv.y)].x, xv.y * sv.y);
        atomicAdd(&z[SW(hv.z)].x, xv.z * sv.z);
        atomicAdd(&z[SW(hv.w)].x, xv.w * sv.w);
        float2 yv = ((const float2*)(y + (size_t)row * 1024))[t];
        float2 tv = ((const float2*)s2)[t];
        int2   hw = ((const int2*)h2)[t];
        atomicAdd(&z[SW(hw.x)].y, yv.x * tv.x);
        atomicAdd(&z[SW(hw.y)].y, yv.y * tv.y);
    }
    __syncthreads();

    float sn, cs;
    float2 v[16];

    // ---------- F1: h=4096,2048,1024,512 ; slot = t + 512m (cross-chunk) ----------
    #pragma unroll
    for (int m = 0; m < 16; ++m) v[m] = z[SW(t + 512 * m)];
    __sincosf(-(float)M_PI / 4096.f * (float)t, &sn, &cs);
    fft16_dif(v, make_float2(cs, sn));
    #pragma unroll
    for (int m = 0; m < 16; ++m) z[SW(t + 512 * m)] = v[m];
    __syncthreads();

    const int cb = wv << 10;   // wave-private 1024-element chunk base

    // ---------- sub-A: slot = cb + l + 64m ; h=256,128,64 ----------
    #pragma unroll
    for (int m = 0; m < 16; ++m) v[m] = z[SW(cb + l + 64 * m)];
    __sincosf(-(float)M_PI / 256.f * (float)l, &sn, &cs);
    fft16_dif3(v, make_float2(cs, sn));
    #pragma unroll
    for (int m = 0; m < 16; ++m) z[SW(cb + l + 64 * m)] = v[m];
    WAVE_SYNC;

    // ---------- sub-B: slot = cb + (l&3) + 4m + 64*(l>>2) ; h=32,16,8,4 ----------
    {
        const int b = cb + (l & 3) + ((l >> 2) << 6);
        #pragma unroll
        for (int m = 0; m < 16; ++m) v[m] = z[SW(b + 4 * m)];
        __sincosf(-(float)M_PI / 32.f * (float)(l & 3), &sn, &cs);
        fft16_dif(v, make_float2(cs, sn));
        #pragma unroll
        for (int m = 0; m < 16; ++m) z[SW(b + 4 * m)] = v[m];
    }
    WAVE_SYNC;

    // ---------- sub-C: slot = cb + 16l + m ; h=2,1 ; results stay in regs ----------
    {
        const int b = cb + 16 * l;
        #pragma unroll
        for (int c = 0; c < 8; ++c) {
            float4 q = *(const float4*)&z[SW(b + 2 * c)];
            v[2 * c]     = make_float2(q.x, q.y);
            v[2 * c + 1] = make_float2(q.z, q.w);
        }
        #pragma unroll
        for (int a = 0; a < 4; ++a) {            // h=2: W = {1, -i}
            bf_dif1 (v[4 * a],     v[4 * a + 2]);
            bf_difmi(v[4 * a + 1], v[4 * a + 3]);
        }
        #pragma unroll
        for (int c = 0; c < 8; ++c) bf_dif1(v[2 * c], v[2 * c + 1]);   // h=1
        #pragma unroll
        for (int c = 0; c < 8; ++c)
            *(float4*)&z[SW(b + 2 * c)] =
                make_float4(v[2 * c].x, v[2 * c].y, v[2 * c + 1].x, v[2 * c + 1].y);
    }
    __syncthreads();

    // ---------- MEGA: pair j=8t+g holds (Z[kappa], Z[kappa+4096]), kappa=512*brev3(g)+brev9(t).
    // Partner pair at thread tp=brev9(512-R), pair 7-g; t==0: own pairs TBL (swap at g==0).
    float2 u[8];
    {
        const int R  = brev9(t);
        const int tp = (R == 0) ? 0 : brev9(512 - R);
        __sincosf((float)M_PI / 4096.f * (float)R, &sn, &cs);
        const float2 wR = make_float2(cs, sn);      // exp(+i*pi*R/4096)
        const float invN = 1.f / 8192.f;
        const int MB[8]  = {0, 4, 2, 6, 1, 5, 3, 7};   // brev3(g)
        const int TBL[8] = {0, 1, 3, 2, 7, 6, 5, 4};
        #pragma unroll
        for (int g = 0; g < 8; ++g) {
            int ps = (t == 0) ? (2 * TBL[g]) : (16 * tp + 2 * (7 - g));
            float4 r = *(const float4*)&z[SW(ps)];
            float2 PA = make_float2(r.x, r.y);
            float2 PB = make_float2(r.z, r.w);
            if (t == 0 && g == 0) { float2 s0 = PA; PA = PB; PB = s0; }   // kappa=0 self-pair
            u[g] = mega_combine(v[2 * g], v[2 * g + 1], PA, PB,
                                cmul(wR, rootI(MB[g])), invN);
        }
        fft8_dit1(u);   // inverse h=1,2,4
    }
    __syncthreads();    // all partner reads complete before overwriting with u
    #pragma unroll
    for (int c = 0; c < 4; ++c)
        *(float4*)&z[SW(8 * t + 2 * c)] =
            make_float4(u[2 * c].x, u[2 * c].y, u[2 * c + 1].x, u[2 * c + 1].y);
    WAVE_SYNC;          // sub-a reads only this wave's own u-writes

    const int b2 = wv << 9;   // wave-private 512-element inverse chunk base

    // ---------- inv sub-a: slot = b2 + (l&7) + 8m + 64*(l>>3) ; h=8,16,32 ----------
    {
        const int b = b2 + (l & 7) + ((l >> 3) << 6);
        #pragma unroll
        for (int m = 0; m < 8; ++m) u[m] = z[SW(b + 8 * m)];
        __sincosf((float)M_PI / 32.f * (float)(l & 7), &sn, &cs);
        fft8_dit(u, make_float2(cs, sn));
        #pragma unroll
        for (int m = 0; m < 8; ++m) z[SW(b + 8 * m)] = u[m];
    }
    WAVE_SYNC;

    // ---------- inv sub-b: slot = b2 + l + 64m ; h=64,128,256 ----------
    {
        const int b = b2 + l;
        #pragma unroll
        for (int m = 0; m < 8; ++m) u[m] = z[SW(b + 64 * m)];
        __sincosf((float)M_PI / 256.f * (float)l, &sn, &cs);
        fft8_dit(u, make_float2(cs, sn));
        #pragma unroll
        for (int m = 0; m < 8; ++m) z[SW(b + 64 * m)] = u[m];
    }
    __syncthreads();

    // ---------- final: slot = t + 512m ; h=512,1024,2048 ; LN + L2 from regs ----------
    #pragma unroll
    for (int m = 0; m < 8; ++m) u[m] = z[SW(t + 512 * m)];
    __sincosf((float)M_PI / 2048.f * (float)t, &sn, &cs);
    fft8_dit(u, make_float2(cs, sn));
    // u[m] = complex at n = t+512m: fused[2n] = .x, fused[2n+1] = .y

    float lsum = 0.f, lsq = 0.f;
    #pragma unroll
    for (int m = 0; m < 8; ++m) {
        lsum += u[m].x + u[m].y;
        lsq  += u[m].x * u[m].x + u[m].y * u[m].y;
    }
    #pragma unroll
    for (int k = 32; k >= 1; k >>= 1) { lsum += __shfl_xor(lsum, k); lsq += __shfl_xor(lsq, k); }
    __syncthreads();                 // all final-sweep reads complete before stash
    if (l == 0) z[wv] = make_float2(lsum, lsq);
    __syncthreads();
    float tsum = 0.f, tsq = 0.f;
    #pragma unroll
    for (int w2 = 0; w2 < 8; ++w2) { tsum += z[w2].x; tsq += z[w2].y; }
    const float mu   = tsum * (1.f / (float)DF);
    const float var  = tsq * (1.f / (float)DF) - mu * mu;
    const float rstd = rsqrtf(var + 1e-5f);

    const float2* g2  = (const float2*)gamma;
    const float2* bt2 = (const float2*)beta;
    float lsq2 = 0.f;
    #pragma unroll
    for (int m = 0; m < 8; ++m) {
        int i = t + 512 * m;
        float2 g = g2[i], bb = bt2[i];
        float ne = (u[m].x - mu) * rstd * g.x + bb.x;
        float no = (u[m].y - mu) * rstd * g.y + bb.y;
        u[m] = make_float2(ne, no);
        lsq2 += ne * ne + no * no;
    }
    #pragma unroll
    for (int k = 32; k >= 1; k >>= 1) lsq2 += __shfl_xor(lsq2, k);
    if (l == 0) z[8 + wv].x = lsq2;
    __syncthreads();
    float t2 = 0.f;
    #pragma unroll
    for (int w2 = 0; w2 < 8; ++w2) t2 += z[8 + w2].x;
    const float inv = 1.f / fmaxf(sqrtf(t2), 1e-12f);

    float2* o2 = (float2*)(out + (size_t)row * DF);
    #pragma unroll
    for (int m = 0; m < 8; ++m)
        o2[t + 512 * m] = make_float2(u[m].x * inv, u[m].y * inv);
}

extern "C" void kernel_launch(void* const* d_in, const int* in_sizes, int n_in,
                              void* d_out, int out_size, void* d_ws, size_t ws_size,
                              hipStream_t stream) {
    const float* x     = (const float*)d_in[0];
    const float* y     = (const float*)d_in[1];
    const float* s1    = (const float*)d_in[2];
    const float* s2    = (const float*)d_in[3];
    const float* gamma = (const float*)d_in[4];
    const float* beta  = (const float*)d_in[5];
    const int*   h1    = (const int*)d_in[6];
    const int*   h2    = (const int*)d_in[7];
    float* out = (float*)d_out;

    hipLaunchKernelGGL(mcb7, dim3(4096), dim3(NT), 0, stream,
                       x, y, s1, s2, gamma, beta, h1, h2, out);
}

// Round 8
// 184.429 us; speedup vs baseline: 1.0750x; 1.0039x over previous
//
#include <hip/hip_runtime.h>
#include <math.h>

#define DF 8192
#define NT 512

// XOR swizzle on float2 slot index: slot bits 1-4 ^= slot bits 4-8 (verified R7:
// conflicts 2.25e7 -> 6.9e6; every structured sweep <=2-way per half-wave).
#define SW(i) ((i) ^ (((i) >> 4) & 30))

// wave-private sync: all my LDS ops complete; compiler may not reorder LDS ops across
#define WAVE_SYNC asm volatile("s_waitcnt lgkmcnt(0)" ::: "memory")

// Packed-fp32 complex: ext_vector ops compile to v_pk_add_f32/v_pk_mul_f32/v_pk_fma_f32
typedef float cf2 __attribute__((ext_vector_type(2)));
typedef float cf4 __attribute__((ext_vector_type(4)));

__device__ __forceinline__ cf2 cswap(cf2 a) { return __builtin_shufflevector(a, a, 1, 0); }        // (ay, ax)
__device__ __forceinline__ cf2 cmuli(cf2 a) { cf2 n = -a; return __builtin_shufflevector(a, n, 3, 0); }  // (-ay, ax) = a*i
__device__ __forceinline__ cf2 cmulmi(cf2 a){ cf2 n = -a; return __builtin_shufflevector(a, n, 1, 2); }  // (ay, -ax) = a*-i
__device__ __forceinline__ cf2 cconj(cf2 a) { cf2 n = -a; return __builtin_shufflevector(a, n, 0, 3); }  // (ax, -ay)
__device__ __forceinline__ cf2 cmul(cf2 a, cf2 b) {
    cf2 bxx = __builtin_shufflevector(b, b, 0, 0);
    cf2 byy = __builtin_shufflevector(b, b, 1, 1);
    return a * bxx + cmuli(a) * byy;   // pk_mul + pk_fma (+ folded neg/op_sel)
}

#define RT_C 0.92387953251128674f
#define RT_S 0.38268343236508977f
#define RT_H 0.70710678118654752f

__device__ __forceinline__ cf2 rootF(int j) {   // exp(-i*pi*j/8)
    switch (j & 7) {
        case 0:  return cf2{ 1.f,   0.f  };
        case 1:  return cf2{ RT_C, -RT_S };
        case 2:  return cf2{ RT_H, -RT_H };
        case 3:  return cf2{ RT_S, -RT_C };
        case 4:  return cf2{ 0.f,  -1.f  };
        case 5:  return cf2{-RT_S, -RT_C };
        case 6:  return cf2{-RT_H, -RT_H };
        default: return cf2{-RT_C, -RT_S };
    }
}
__device__ __forceinline__ cf2 rootI(int j) { return cconj(rootF(j)); }   // exp(+i*pi*j/8)

__device__ __forceinline__ int brev9(int x) { return (int)(__brev((unsigned)x) >> 23); }

// ---- butterflies (packed) ----
__device__ __forceinline__ void bf_dif(cf2& a, cf2& b, cf2 W) {
    cf2 d = a - b;
    a = a + b;
    b = cmul(d, W);
}
__device__ __forceinline__ void bf_dif1(cf2& a, cf2& b)  { cf2 d = a - b; a = a + b; b = d; }
__device__ __forceinline__ void bf_difmi(cf2& a, cf2& b) { cf2 d = a - b; a = a + b; b = cmulmi(d); }
__device__ __forceinline__ void bf_dit(cf2& a, cf2& b, cf2 W) {
    cf2 bw = cmul(b, W);
    cf2 ta = a;
    a = ta + bw;
    b = ta - bw;
}
__device__ __forceinline__ void bf_dit1(cf2& a, cf2& b) { cf2 tb = b, ta = a; a = ta + tb; b = ta - tb; }
__device__ __forceinline__ void bf_diti(cf2& a, cf2& b) { cf2 bw = cmuli(b); cf2 ta = a; a = ta + bw; b = ta - bw; }

// 4 radix-2 DIF stages on 16 register elements, base twiddle wb (verified R3).
__device__ __forceinline__ void fft16_dif(cf2 v[16], cf2 wb) {
    const cf2 wb2 = cmul(wb, wb);
    const cf2 wb4 = cmul(wb2, wb2);
    const cf2 wb8 = cmul(wb4, wb4);
    #pragma unroll
    for (int m = 0; m < 8; ++m) bf_dif(v[m], v[m + 8], cmul(wb, rootF(m)));
    #pragma unroll
    for (int m = 0; m < 4; ++m) {
        cf2 W = cmul(wb2, rootF(2 * m));
        bf_dif(v[m],     v[m + 4],  W);
        bf_dif(v[8 + m], v[12 + m], W);
    }
    #pragma unroll
    for (int g = 0; g < 4; ++g)
        #pragma unroll
        for (int m = 0; m < 2; ++m)
            bf_dif(v[4 * g + m], v[4 * g + m + 2], cmul(wb4, rootF(4 * m)));
    #pragma unroll
    for (int g = 0; g < 8; ++g) bf_dif(v[2 * g], v[2 * g + 1], wb8);
}

// 3 radix-2 DIF stages (dm=4,2,1) for sub-A: h=256,128,64; wA = exp(-i*pi*l/256).
__device__ __forceinline__ void fft16_dif3(cf2 v[16], cf2 wA) {
    const cf2 wA2 = cmul(wA, wA);
    const cf2 wA4 = cmul(wA2, wA2);
    #pragma unroll
    for (int m = 0; m < 4; ++m) {
        cf2 W = cmul(wA, rootF(2 * m));
        bf_dif(v[m],     v[m + 4],  W);
        bf_dif(v[8 + m], v[12 + m], W);
    }
    #pragma unroll
    for (int a = 0; a < 4; ++a)
        #pragma unroll
        for (int q = 0; q < 2; ++q)
            bf_dif(v[4 * a + q], v[4 * a + q + 2], cmul(wA2, rootF(4 * q)));
    #pragma unroll
    for (int c = 0; c < 8; ++c)
        bf_dif(v[2 * c], v[2 * c + 1], wA4);
}

// 3 radix-2 DIT stages on 8 elements; wq = exp(+i*pi*k/(4*h_first)) (verified R3/R5).
__device__ __forceinline__ void fft8_dit(cf2 v[8], cf2 wq) {
    const cf2 wq2 = cmul(wq, wq);
    const cf2 wq4 = cmul(wq2, wq2);
    #pragma unroll
    for (int g = 0; g < 4; ++g) bf_dit(v[2 * g], v[2 * g + 1], wq4);
    const cf2 iwq2 = cmuli(wq2);
    #pragma unroll
    for (int g = 0; g < 2; ++g) {
        bf_dit(v[4 * g],     v[4 * g + 2], wq2);
        bf_dit(v[4 * g + 1], v[4 * g + 3], iwq2);
    }
    bf_dit(v[0], v[4], wq);
    bf_dit(v[1], v[5], cmul(wq, cf2{RT_H, RT_H}));
    bf_dit(v[2], v[6], cmuli(wq));
    bf_dit(v[3], v[7], cmul(wq, cf2{-RT_H, RT_H}));
}
__device__ __forceinline__ void fft8_dit1(cf2 v[8]) {
    #pragma unroll
    for (int g = 0; g < 4; ++g) bf_dit1(v[2 * g], v[2 * g + 1]);
    #pragma unroll
    for (int g = 0; g < 2; ++g) {
        bf_dit1(v[4 * g],     v[4 * g + 2]);
        bf_diti(v[4 * g + 1], v[4 * g + 3]);
    }
    bf_dit1(v[0], v[4]);
    bf_dit (v[1], v[5], cf2{RT_H, RT_H});
    bf_diti(v[2], v[6]);
    bf_dit (v[3], v[7], cf2{-RT_H, RT_H});
}

// Hermitian product + half-size-IFFT input prep (verified R3/R5), packed form.
// P1 = [ (A+conj PB)/2 * (-i)(A-conj PB)/2 ]/N ; note (-i)(A-conj PB)/2 = (cmulmi(A)+cswap(PB))/2.
__device__ __forceinline__ cf2 mega_combine(cf2 A, cf2 B, cf2 PA, cf2 PB, cf2 W, float q) {
    cf2 P1 = cmul(A + cconj(PB), cmulmi(A) + cswap(PB)) * q;   // q = 0.25/N
    cf2 P2 = cmul(B + cconj(PA), cmulmi(B) + cswap(PA)) * q;
    cf2 S = P1 + P2;
    cf2 Dw = cmul(P1 - P2, W);
    return S + cmuli(Dw);
}

// Structure identical to R7: F1 | sub-A | sub-B | sub-C | MEGA | inv sub-a | inv sub-b | final | LN+L2.
__global__ __launch_bounds__(NT, 4)
void mcb8(const float* __restrict__ x, const float* __restrict__ y,
          const float* __restrict__ s1, const float* __restrict__ s2,
          const float* __restrict__ gamma, const float* __restrict__ beta,
          const int* __restrict__ h1, const int* __restrict__ h2,
          float* __restrict__ out)
{
    __shared__ cf2 z[DF];   // 64 KB
    float* zf = (float*)z;
    const int t  = threadIdx.x;
    const int l  = t & 63;
    const int wv = t >> 6;
    const int row = blockIdx.x;

    // ---- zero ----
    {
        cf4* z4 = (cf4*)z;
        #pragma unroll
        for (int m = 0; m < 8; ++m) z4[t + NT * m] = cf4{0.f, 0.f, 0.f, 0.f};
    }
    __syncthreads();

    // ---- count sketches: x*s1 -> .x, y*s2 -> .y ----
    {
        float4 xv = ((const float4*)(x + (size_t)row * 2048))[t];
        float4 sv = ((const float4*)s1)[t];
        int4   hv = ((const int4*)h1)[t];
        atomicAdd(zf + 2 * SW(hv.x), xv.x * sv.x);
        atomicAdd(zf + 2 * SW(hv.y), xv.y * sv.y);
        atomicAdd(zf + 2 * SW(hv.z), xv.z * sv.z);
        atomicAdd(zf + 2 * SW(hv.w), xv.w * sv.w);
        float2 yv = ((const float2*)(y + (size_t)row * 1024))[t];
        float2 tv = ((const float2*)s2)[t];
        int2   hw = ((const int2*)h2)[t];
        atomicAdd(zf + 2 * SW(hw.x) + 1, yv.x * tv.x);
        atomicAdd(zf + 2 * SW(hw.y) + 1, yv.y * tv.y);
    }
    __syncthreads();

    float sn, cs;
    cf2 v[16];

    // ---------- F1: h=4096,2048,1024,512 ; slot = t + 512m (cross-chunk) ----------
    #pragma unroll
    for (int m = 0; m < 16; ++m) v[m] = z[SW(t + 512 * m)];
    __sincosf(-(float)M_PI / 4096.f * (float)t, &sn, &cs);
    fft16_dif(v, cf2{cs, sn});
    #pragma unroll
    for (int m = 0; m < 16; ++m) z[SW(t + 512 * m)] = v[m];
    __syncthreads();

    const int cb = wv << 10;   // wave-private 1024-element chunk base

    // ---------- sub-A: slot = cb + l + 64m ; h=256,128,64 ----------
    #pragma unroll
    for (int m = 0; m < 16; ++m) v[m] = z[SW(cb + l + 64 * m)];
    __sincosf(-(float)M_PI / 256.f * (float)l, &sn, &cs);
    fft16_dif3(v, cf2{cs, sn});
    #pragma unroll
    for (int m = 0; m < 16; ++m) z[SW(cb + l + 64 * m)] = v[m];
    WAVE_SYNC;

    // ---------- sub-B: slot = cb + (l&3) + 4m + 64*(l>>2) ; h=32,16,8,4 ----------
    {
        const int b = cb + (l & 3) + ((l >> 2) << 6);
        #pragma unroll
        for (int m = 0; m < 16; ++m) v[m] = z[SW(b + 4 * m)];
        __sincosf(-(float)M_PI / 32.f * (float)(l & 3), &sn, &cs);
        fft16_dif(v, cf2{cs, sn});
        #pragma unroll
        for (int m = 0; m < 16; ++m) z[SW(b + 4 * m)] = v[m];
    }
    WAVE_SYNC;

    // ---------- sub-C: slot = cb + 16l + m ; h=2,1 ; results stay in regs ----------
    {
        const int b = cb + 16 * l;
        #pragma unroll
        for (int c = 0; c < 8; ++c) {
            cf4 q = *(const cf4*)&z[SW(b + 2 * c)];
            v[2 * c]     = q.lo;
            v[2 * c + 1] = q.hi;
        }
        #pragma unroll
        for (int a = 0; a < 4; ++a) {            // h=2: W = {1, -i}
            bf_dif1 (v[4 * a],     v[4 * a + 2]);
            bf_difmi(v[4 * a + 1], v[4 * a + 3]);
        }
        #pragma unroll
        for (int c = 0; c < 8; ++c) bf_dif1(v[2 * c], v[2 * c + 1]);   // h=1
        #pragma unroll
        for (int c = 0; c < 8; ++c) {
            cf4 q;
            q.lo = v[2 * c];
            q.hi = v[2 * c + 1];
            *(cf4*)&z[SW(b + 2 * c)] = q;
        }
    }
    __syncthreads();

    // ---------- MEGA: pair j=8t+g holds (Z[kappa], Z[kappa+4096]), kappa=512*brev3(g)+brev9(t).
    // Partner pair at thread tp=brev9(512-R), pair 7-g; t==0: own pairs TBL (swap at g==0).
    cf2 u[8];
    {
        const int R  = brev9(t);
        const int tp = (R == 0) ? 0 : brev9(512 - R);
        __sincosf((float)M_PI / 4096.f * (float)R, &sn, &cs);
        const cf2 wR = cf2{cs, sn};                 // exp(+i*pi*R/4096)
        const float q4 = 0.25f / 8192.f;            // folded 0.5*0.5*invN
        const int MB[8]  = {0, 4, 2, 6, 1, 5, 3, 7};   // brev3(g)
        const int TBL[8] = {0, 1, 3, 2, 7, 6, 5, 4};
        #pragma unroll
        for (int g = 0; g < 8; ++g) {
            int ps = (t == 0) ? (2 * TBL[g]) : (16 * tp + 2 * (7 - g));
            cf4 r = *(const cf4*)&z[SW(ps)];
            cf2 PA = r.lo, PB = r.hi;
            if (t == 0 && g == 0) { cf2 s0 = PA; PA = PB; PB = s0; }   // kappa=0 self-pair
            u[g] = mega_combine(v[2 * g], v[2 * g + 1], PA, PB,
                                cmul(wR, rootI(MB[g])), q4);
        }
        fft8_dit1(u);   // inverse h=1,2,4
    }
    __syncthreads();    // all partner reads complete before overwriting with u
    #pragma unroll
    for (int c = 0; c < 4; ++c) {
        cf4 q;
        q.lo = u[2 * c];
        q.hi = u[2 * c + 1];
        *(cf4*)&z[SW(8 * t + 2 * c)] = q;
    }
    WAVE_SYNC;          // sub-a reads only this wave's own u-writes

    const int b2 = wv << 9;   // wave-private 512-element inverse chunk base

    // ---------- inv sub-a: slot = b2 + (l&7) + 8m + 64*(l>>3) ; h=8,16,32 ----------
    {
        const int b = b2 + (l & 7) + ((l >> 3) << 6);
        #pragma unroll
        for (int m = 0; m < 8; ++m) u[m] = z[SW(b + 8 * m)];
        __sincosf((float)M_PI / 32.f * (float)(l & 7), &sn, &cs);
        fft8_dit(u, cf2{cs, sn});
        #pragma unroll
        for (int m = 0; m < 8; ++m) z[SW(b + 8 * m)] = u[m];
    }
    WAVE_SYNC;

    // ---------- inv sub-b: slot = b2 + l + 64m ; h=64,128,256 ----------
    {
        const int b = b2 + l;
        #pragma unroll
        for (int m = 0; m < 8; ++m) u[m] = z[SW(b + 64 * m)];
        __sincosf((float)M_PI / 256.f * (float)l, &sn, &cs);
        fft8_dit(u, cf2{cs, sn});
        #pragma unroll
        for (int m = 0; m < 8; ++m) z[SW(b + 64 * m)] = u[m];
    }
    __syncthreads();

    // ---------- final: slot = t + 512m ; h=512,1024,2048 ; LN + L2 from regs ----------
    #pragma unroll
    for (int m = 0; m < 8; ++m) u[m] = z[SW(t + 512 * m)];
    __sincosf((float)M_PI / 2048.f * (float)t, &sn, &cs);
    fft8_dit(u, cf2{cs, sn});
    // u[m] = complex at n = t+512m: fused[2n] = .x, fused[2n+1] = .y

    float lsum = 0.f, lsq = 0.f;
    #pragma unroll
    for (int m = 0; m < 8; ++m) {
        lsum += u[m].x + u[m].y;
        lsq  += u[m].x * u[m].x + u[m].y * u[m].y;
    }
    #pragma unroll
    for (int k = 32; k >= 1; k >>= 1) { lsum += __shfl_xor(lsum, k); lsq += __shfl_xor(lsq, k); }
    __syncthreads();                 // all final-sweep reads complete before stash
    if (l == 0) z[wv] = cf2{lsum, lsq};
    __syncthreads();
    float tsum = 0.f, tsq = 0.f;
    #pragma unroll
    for (int w2 = 0; w2 < 8; ++w2) { cf2 s = z[w2]; tsum += s.x; tsq += s.y; }
    const float mu   = tsum * (1.f / (float)DF);
    const float var  = tsq * (1.f / (float)DF) - mu * mu;
    const float rstd = rsqrtf(var + 1e-5f);

    const cf2* g2  = (const cf2*)gamma;
    const cf2* bt2 = (const cf2*)beta;
    float lsq2 = 0.f;
    #pragma unroll
    for (int m = 0; m < 8; ++m) {
        int i = t + 512 * m;
        cf2 nv = (u[m] - mu) * rstd * g2[i] + bt2[i];   // pk fma chain
        u[m] = nv;
        lsq2 += nv.x * nv.x + nv.y * nv.y;
    }
    #pragma unroll
    for (int k = 32; k >= 1; k >>= 1) lsq2 += __shfl_xor(lsq2, k);
    if (l == 0) zf[2 * (8 + wv)] = lsq2;
    __syncthreads();
    float t2 = 0.f;
    #pragma unroll
    for (int w2 = 0; w2 < 8; ++w2) t2 += zf[2 * (8 + w2)];
    const float inv = 1.f / fmaxf(sqrtf(t2), 1e-12f);

    cf2* o2 = (cf2*)(out + (size_t)row * DF);
    #pragma unroll
    for (int m = 0; m < 8; ++m)
        o2[t + 512 * m] = u[m] * inv;
}

extern "C" void kernel_launch(void* const* d_in, const int* in_sizes, int n_in,
                              void* d_out, int out_size, void* d_ws, size_t ws_size,
                              hipStream_t stream) {
    const float* x     = (const float*)d_in[0];
    const float* y     = (const float*)d_in[1];
    const float* s1    = (const float*)d_in[2];
    const float* s2    = (const float*)d_in[3];
    const float* gamma = (const float*)d_in[4];
    const float* beta  = (const float*)d_in[5];
    const int*   h1    = (const int*)d_in[6];
    const int*   h2    = (const int*)d_in[7];
    float* out = (float*)d_out;

    hipLaunchKernelGGL(mcb8, dim3(4096), dim3(NT), 0, stream,
                       x, y, s1, s2, gamma, beta, h1, h2, out);
}